// Round 3
// baseline (176.024 us; speedup 1.0000x reference)
//
#include <hip/hip_runtime.h>

#define CUTOFF 5.0f
#define DEPS 1e-12f

// d_ws float layout:
// acc[0]  ligand coord-loss sum of per-batch ratios
// acc[3]  sidechain mse*am sum
// acc[4]  sidechain am sum
// acc[5]  sidechain dist val sum
// acc[6]  sidechain has count
// acc[7]  (as uint) done-block counter
// acc+8   bnum[64] per-batch ligand pair num
// acc+72  bden[64] per-batch ligand pair den
// zeroed: 136 floats

#define NSC_BLK 512    // sidechain: 512 blocks * 128 thr = 65536 groups
#define NLIG_BLK 1024  // ligand: 64 batches * 16 i-tiles
#define GRID (NSC_BLK + NLIG_BLK)

__global__ __launch_bounds__(128) void fused_kernel(
    const float* __restrict__ lig_pred, const float* __restrict__ lig_tgt,
    const int* __restrict__ lig_mask,
    const float* __restrict__ sc_pred, const float* __restrict__ sc_tgt,
    const int* __restrict__ sc_mask,
    float* __restrict__ acc, float* __restrict__ out) {
  float* bnum = acc + 8;
  float* bden = acc + 72;
  unsigned int* done = (unsigned int*)(acc + 7);
  const int tid = threadIdx.x;

  __shared__ float4 st4[32];   // ligand i-tile: tgt xyz + mask
  __shared__ float4 sp4[32];   // ligand i-tile: pred xyz
  __shared__ float red[4][2];
  __shared__ bool last;

  if (blockIdx.x < NSC_BLK) {
    // ---------------- sidechain: one thread per (b,r) group ----------------
    const int A = 14;
    const int g = blockIdx.x * 128 + tid;
    const float2* pg = (const float2*)(sc_pred + (size_t)g * A * 3);
    const float2* tg = (const float2*)(sc_tgt + (size_t)g * A * 3);
    const int2* mg = (const int2*)(sc_mask + (size_t)g * A);

    float2 pbuf[21], tbuf[21];
#pragma unroll
    for (int k = 0; k < 21; k++) { pbuf[k] = pg[k]; tbuf[k] = tg[k]; }
    int mi_[14];
#pragma unroll
    for (int k = 0; k < 7; k++) { int2 v = mg[k]; mi_[2 * k] = v.x; mi_[2 * k + 1] = v.y; }
    const float* pf = (const float*)pbuf;
    const float* tf = (const float*)tbuf;

    float m[14], px[14], py[14], pz[14], tx[14], ty[14], tz[14];
    float mse_sum = 0.f, am_sum = 0.f;
#pragma unroll
    for (int a = 0; a < A; a++) {
      m[a] = (mi_[a] != 0) ? 1.f : 0.f;
      px[a] = pf[3 * a]; py[a] = pf[3 * a + 1]; pz[a] = pf[3 * a + 2];
      tx[a] = tf[3 * a]; ty[a] = tf[3 * a + 1]; tz[a] = tf[3 * a + 2];
      float dx = px[a] - tx[a], dy = py[a] - ty[a], dz = pz[a] - tz[a];
      mse_sum += m[a] * ((dx * dx + dy * dy + dz * dz) * (1.f / 3.f));
      am_sum += m[a];
    }
    float num = 0.f, den = 0.f;
#pragma unroll
    for (int i = 0; i < A; i++) {
#pragma unroll
      for (int j = i + 1; j < A; j++) {
        float w = m[i] * m[j];
        float dx = tx[i] - tx[j], dy = ty[i] - ty[j], dz = tz[i] - tz[j];
        float tsq = dx * dx + dy * dy + dz * dz;
        float td = sqrtf(fmaxf(tsq, DEPS));
        w = (tsq > 0.f) ? w : 0.f;
        w = (td <= CUTOFF) ? w : 0.f;
        float qx = px[i] - px[j], qy = py[i] - py[j], qz = pz[i] - pz[j];
        float pd = sqrtf(fmaxf(qx * qx + qy * qy + qz * qz, DEPS));
        float d = pd - td;
        num += w * d * d;
        den += w;
      }
    }
    float has = (den > 0.f) ? 1.f : 0.f;
    float val = (den > 0.f) ? num / fmaxf(den, 1.f) : 0.f;

    for (int off = 32; off > 0; off >>= 1) {
      mse_sum += __shfl_down(mse_sum, off, 64);
      am_sum += __shfl_down(am_sum, off, 64);
      val += __shfl_down(val, off, 64);
      has += __shfl_down(has, off, 64);
    }
    int lane = tid & 63, wv = tid >> 6;
    if (lane == 0) { red[0][wv] = mse_sum; red[1][wv] = am_sum; red[2][wv] = val; red[3][wv] = has; }
    __syncthreads();
    if (tid == 0) {
      atomicAdd(&acc[3], red[0][0] + red[0][1]);
      atomicAdd(&acc[4], red[1][0] + red[1][1]);
      atomicAdd(&acc[5], red[2][0] + red[2][1]);
      atomicAdd(&acc[6], red[3][0] + red[3][1]);
    }
  } else {
    // ---------------- ligand: block = (batch, 32-wide i-tile) ----------------
    const int L = 512;
    const int lb = blockIdx.x - NSC_BLK;
    const int b = lb >> 4;
    const int tile = lb & 15;
    const int i0 = tile * 32;
    const float* pb = lig_pred + (size_t)b * L * 3;
    const float* tb = lig_tgt + (size_t)b * L * 3;
    const int* mb = lig_mask + (size_t)b * L;

    // 4 j-atoms per thread, held in registers (coalesced 12B/lane loads)
    float pjx[4], pjy[4], pjz[4], tjx[4], tjy[4], tjz[4], mj[4];
#pragma unroll
    for (int k = 0; k < 4; k++) {
      int j = k * 128 + tid;
      pjx[k] = pb[3 * j]; pjy[k] = pb[3 * j + 1]; pjz[k] = pb[3 * j + 2];
      tjx[k] = tb[3 * j]; tjy[k] = tb[3 * j + 1]; tjz[k] = tb[3 * j + 2];
      mj[k] = (mb[j] != 0) ? 1.f : 0.f;
    }
    // stage the 32-atom i-tile into LDS (float4 => broadcast ds_read_b128)
    if (tid < 32) {
      int i = i0 + tid;
      st4[tid] = make_float4(tb[3 * i], tb[3 * i + 1], tb[3 * i + 2], (mb[i] != 0) ? 1.f : 0.f);
    } else if (tid < 64) {
      int i = i0 + tid - 32;
      sp4[tid - 32] = make_float4(pb[3 * i], pb[3 * i + 1], pb[3 * i + 2], 0.f);
    }
    __syncthreads();

    // coord term from the j registers (tile 0 only; covers all 512 atoms)
    float se = 0.f, cnt = 0.f;
    if (tile == 0) {
#pragma unroll
      for (int k = 0; k < 4; k++) {
        float dx = pjx[k] - tjx[k], dy = pjy[k] - tjy[k], dz = pjz[k] - tjz[k];
        se += mj[k] * (dx * dx + dy * dy + dz * dz);
        cnt += mj[k];
      }
    }

    // full-matrix pair term for this i-tile (matches reference exactly;
    // diagonal killed by tsq>0)
    float num = 0.f, den = 0.f;
#pragma unroll 4
    for (int ii = 0; ii < 32; ii++) {
      float4 ti = st4[ii];
      float4 pi = sp4[ii];
#pragma unroll
      for (int k = 0; k < 4; k++) {
        float w = ti.w * mj[k];
        float dx = ti.x - tjx[k], dy = ti.y - tjy[k], dz = ti.z - tjz[k];
        float tsq = dx * dx + dy * dy + dz * dz;
        float td = sqrtf(fmaxf(tsq, DEPS));
        w = (tsq > 0.f) ? w : 0.f;
        w = (td <= CUTOFF) ? w : 0.f;
        float qx = pi.x - pjx[k], qy = pi.y - pjy[k], qz = pi.z - pjz[k];
        float pd = sqrtf(fmaxf(qx * qx + qy * qy + qz * qz, DEPS));
        float d = pd - td;
        num += w * d * d;
        den += w;
      }
    }

    for (int off = 32; off > 0; off >>= 1) {
      num += __shfl_down(num, off, 64);
      den += __shfl_down(den, off, 64);
      se += __shfl_down(se, off, 64);
      cnt += __shfl_down(cnt, off, 64);
    }
    int lane = tid & 63, wv = tid >> 6;
    if (lane == 0) { red[0][wv] = num; red[1][wv] = den; red[2][wv] = se; red[3][wv] = cnt; }
    __syncthreads();
    if (tid == 0) {
      atomicAdd(&bnum[b], red[0][0] + red[0][1]);
      atomicAdd(&bden[b], red[1][0] + red[1][1]);
      if (tile == 0) {
        float se_t = red[2][0] + red[2][1], cnt_t = red[3][0] + red[3][1];
        atomicAdd(&acc[0], se_t / (3.f * fmaxf(cnt_t, 1.f)));
      }
    }
  }

  // ---------------- last-block finalize ----------------
  if (tid == 0) {
    __threadfence();
    unsigned int old = atomicAdd(done, 1u);
    last = (old == GRID - 1);
  }
  __syncthreads();
  if (last && tid < 64) {
    // atomic read-backs: device-scope coherent view of other blocks' adds
    float n = atomicAdd(&bnum[tid], 0.f);
    float d = atomicAdd(&bden[tid], 0.f);
    float val = (d > 0.f) ? n / fmaxf(d, 1.f) : 0.f;
    float has = (d > 0.f) ? 1.f : 0.f;
    for (int off = 32; off > 0; off >>= 1) {
      val += __shfl_down(val, off, 64);
      has += __shfl_down(has, off, 64);
    }
    if (tid == 0) {
      float lig = atomicAdd(&acc[0], 0.f) * (1.f / 64.f);
      float sc_mse = atomicAdd(&acc[3], 0.f);
      float sc_am = atomicAdd(&acc[4], 0.f);
      float sc_val = atomicAdd(&acc[5], 0.f);
      float sc_has = atomicAdd(&acc[6], 0.f);
      float ligand_dist_loss = val / fmaxf(has, 1.f);
      float sidechain_loss = sc_mse / fmaxf(sc_am, 1.f);
      float sidechain_dist_loss = sc_val / fmaxf(sc_has, 1.f);
      out[0] = lig + 0.2f * ligand_dist_loss + 0.5f * sidechain_loss +
               0.1f * sidechain_dist_loss;
    }
  }
}

extern "C" void kernel_launch(void* const* d_in, const int* in_sizes, int n_in,
                              void* d_out, int out_size, void* d_ws, size_t ws_size,
                              hipStream_t stream) {
  const float* ligand_pred = (const float*)d_in[0];
  const float* ligand_tgt = (const float*)d_in[1];
  const float* sidechain_pred = (const float*)d_in[2];
  const float* sidechain_tgt = (const float*)d_in[3];
  const int* ligand_mask = (const int*)d_in[4];
  const int* atom_mask = (const int*)d_in[5];
  float* out = (float*)d_out;
  float* acc = (float*)d_ws;

  hipMemsetAsync(acc, 0, 136 * sizeof(float), stream);
  fused_kernel<<<GRID, 128, 0, stream>>>(ligand_pred, ligand_tgt, ligand_mask,
                                         sidechain_pred, sidechain_tgt, atom_mask,
                                         acc, out);
}

// Round 4
// 107.773 us; speedup vs baseline: 1.6333x; 1.6333x over previous
//
#include <hip/hip_runtime.h>

#define CUTOFF 5.0f
#define DEPS 1e-12f
#define FSQRT(x) __builtin_amdgcn_sqrtf(x)

// ws float layout (all slots written unconditionally every launch):
//  [0, 2048)     lig_part[1024][2]  (num, den) per ligand block
//  [2048, 2112)  lig_coord[64]      per-batch coord ratio (tile-0 blocks)
//  [2112, 4160)  sc_part[512][4]    (mse, am, val, has) per sidechain block

#define NSC_BLK 512    // 512 blocks * 128 groups (2 lanes/group, 256 thr)
#define NLIG_BLK 1024  // 64 batches * 16 i-tiles
#define GRID (NSC_BLK + NLIG_BLK)

__global__ __launch_bounds__(256) void fused_kernel(
    const float* __restrict__ lig_pred, const float* __restrict__ lig_tgt,
    const int* __restrict__ lig_mask,
    const float* __restrict__ sc_pred, const float* __restrict__ sc_tgt,
    const int* __restrict__ sc_mask,
    float* __restrict__ ws) {
  const int tid = threadIdx.x;
  __shared__ float4 stage4[1344];  // 21.5 KB; sc staging / ligand i-tiles (aliased)
  __shared__ float red[4][4];

  if (blockIdx.x < NSC_BLK) {
    // ================= sidechain: 2 lanes per group =================
    // lane = 2*gl + p; lane owns atoms [p*7, p*7+7) of group gl.
    float ax[7], ay[7], az[7];  // pred, own atoms
    float bx[7], by[7], bz[7];  // tgt, own atoms
    float m[7];

    // stage pred chunk (128 groups * 42 floats = 5376 floats) coalesced
    const float4* srcp = (const float4*)(sc_pred + (size_t)blockIdx.x * 5376);
    for (int k = tid; k < 1344; k += 256) stage4[k] = srcp[k];
    __syncthreads();
    {
      const float* s = ((const float*)stage4) + tid * 21;  // gcd(21,32)=1: no conflicts
#pragma unroll
      for (int a = 0; a < 7; a++) { ax[a] = s[3 * a]; ay[a] = s[3 * a + 1]; az[a] = s[3 * a + 2]; }
    }
    __syncthreads();
    const float4* srct = (const float4*)(sc_tgt + (size_t)blockIdx.x * 5376);
    for (int k = tid; k < 1344; k += 256) stage4[k] = srct[k];
    __syncthreads();
    {
      const float* s = ((const float*)stage4) + tid * 21;
#pragma unroll
      for (int a = 0; a < 7; a++) { bx[a] = s[3 * a]; by[a] = s[3 * a + 1]; bz[a] = s[3 * a + 2]; }
    }
    // masks: 7 ints/lane, contiguous per lane
    const int* mp = sc_mask + (size_t)blockIdx.x * 1792 + tid * 7;
#pragma unroll
    for (int a = 0; a < 7; a++) m[a] = (mp[a] != 0) ? 1.f : 0.f;

    // per-atom coord mse over own half
    float mse = 0.f, am = 0.f;
#pragma unroll
    for (int a = 0; a < 7; a++) {
      float dx = ax[a] - bx[a], dy = ay[a] - by[a], dz = az[a] - bz[a];
      mse += m[a] * ((dx * dx + dy * dy + dz * dz) * (1.f / 3.f));
      am += m[a];
    }

    // pair loop: i over own 7, j over all 14 (own + partner via shfl_xor).
    // Full ordered matrix across the lane pair == reference's dmask sum;
    // diagonal i==j gives tsq==0 exactly -> excluded.
    float num = 0.f, den = 0.f;
#pragma unroll
    for (int js = 0; js < 7; js++) {
#pragma unroll
      for (int side = 0; side < 2; side++) {
        float jx, jy, jz, kx, ky, kz, mj;
        if (side == 0) {
          jx = ax[js]; jy = ay[js]; jz = az[js];
          kx = bx[js]; ky = by[js]; kz = bz[js];
          mj = m[js];
        } else {
          jx = __shfl_xor(ax[js], 1, 64); jy = __shfl_xor(ay[js], 1, 64);
          jz = __shfl_xor(az[js], 1, 64);
          kx = __shfl_xor(bx[js], 1, 64); ky = __shfl_xor(by[js], 1, 64);
          kz = __shfl_xor(bz[js], 1, 64);
          mj = __shfl_xor(m[js], 1, 64);
        }
#pragma unroll
        for (int i = 0; i < 7; i++) {
          float dx = bx[i] - kx, dy = by[i] - ky, dz = bz[i] - kz;
          float tsq = dx * dx + dy * dy + dz * dz;
          float td = FSQRT(fmaxf(tsq, DEPS));
          float w = m[i] * mj;
          w = (tsq > 0.f) ? w : 0.f;
          w = (td <= CUTOFF) ? w : 0.f;
          float qx = ax[i] - jx, qy = ay[i] - jy, qz = az[i] - jz;
          float pd = FSQRT(fmaxf(qx * qx + qy * qy + qz * qz, DEPS));
          float d = pd - td;
          num += w * d * d;
          den += w;
        }
      }
    }
    // combine lane pair -> per-group val/has; each lane contributes half
    float num_g = num + __shfl_xor(num, 1, 64);
    float den_g = den + __shfl_xor(den, 1, 64);
    float val = (den_g > 0.f) ? 0.5f * (num_g / fmaxf(den_g, 1.f)) : 0.f;
    float has = (den_g > 0.f) ? 0.5f : 0.f;

    for (int off = 32; off > 0; off >>= 1) {
      mse += __shfl_down(mse, off, 64);
      am += __shfl_down(am, off, 64);
      val += __shfl_down(val, off, 64);
      has += __shfl_down(has, off, 64);
    }
    int lane = tid & 63, wv = tid >> 6;
    if (lane == 0) { red[0][wv] = mse; red[1][wv] = am; red[2][wv] = val; red[3][wv] = has; }
    __syncthreads();
    if (tid == 0) {
      float* p = ws + 2112 + (size_t)blockIdx.x * 4;
      p[0] = red[0][0] + red[0][1] + red[0][2] + red[0][3];
      p[1] = red[1][0] + red[1][1] + red[1][2] + red[1][3];
      p[2] = red[2][0] + red[2][1] + red[2][2] + red[2][3];
      p[3] = red[3][0] + red[3][1] + red[3][2] + red[3][3];
    }
  } else {
    // ================= ligand: block = (batch, 32-wide i-tile) =================
    const int L = 512;
    const int lb = blockIdx.x - NSC_BLK;
    const int b = lb >> 4;
    const int tile = lb & 15;
    const int i0 = tile * 32;
    const float* pb = lig_pred + (size_t)b * L * 3;
    const float* tb = lig_tgt + (size_t)b * L * 3;
    const int* mb = lig_mask + (size_t)b * L;

    float4* st4 = stage4;       // i-tile tgt xyz + mask
    float4* sp4 = stage4 + 32;  // i-tile pred xyz

    // 2 j-atoms per thread in registers
    float pjx[2], pjy[2], pjz[2], tjx[2], tjy[2], tjz[2], mj[2];
#pragma unroll
    for (int k = 0; k < 2; k++) {
      int j = k * 256 + tid;
      pjx[k] = pb[3 * j]; pjy[k] = pb[3 * j + 1]; pjz[k] = pb[3 * j + 2];
      tjx[k] = tb[3 * j]; tjy[k] = tb[3 * j + 1]; tjz[k] = tb[3 * j + 2];
      mj[k] = (mb[j] != 0) ? 1.f : 0.f;
    }
    if (tid < 32) {
      int i = i0 + tid;
      st4[tid] = make_float4(tb[3 * i], tb[3 * i + 1], tb[3 * i + 2], (mb[i] != 0) ? 1.f : 0.f);
    } else if (tid < 64) {
      int i = i0 + tid - 32;
      sp4[tid - 32] = make_float4(pb[3 * i], pb[3 * i + 1], pb[3 * i + 2], 0.f);
    }
    __syncthreads();

    float se = 0.f, cnt = 0.f;
    if (tile == 0) {
#pragma unroll
      for (int k = 0; k < 2; k++) {
        float dx = pjx[k] - tjx[k], dy = pjy[k] - tjy[k], dz = pjz[k] - tjz[k];
        se += mj[k] * (dx * dx + dy * dy + dz * dz);
        cnt += mj[k];
      }
    }

    float num = 0.f, den = 0.f;
#pragma unroll 4
    for (int ii = 0; ii < 32; ii++) {
      float4 ti = st4[ii];
      float4 pi = sp4[ii];
#pragma unroll
      for (int k = 0; k < 2; k++) {
        float w = ti.w * mj[k];
        float dx = ti.x - tjx[k], dy = ti.y - tjy[k], dz = ti.z - tjz[k];
        float tsq = dx * dx + dy * dy + dz * dz;
        float td = FSQRT(fmaxf(tsq, DEPS));
        w = (tsq > 0.f) ? w : 0.f;
        w = (td <= CUTOFF) ? w : 0.f;
        float qx = pi.x - pjx[k], qy = pi.y - pjy[k], qz = pi.z - pjz[k];
        float pd = FSQRT(fmaxf(qx * qx + qy * qy + qz * qz, DEPS));
        float d = pd - td;
        num += w * d * d;
        den += w;
      }
    }

    for (int off = 32; off > 0; off >>= 1) {
      num += __shfl_down(num, off, 64);
      den += __shfl_down(den, off, 64);
      se += __shfl_down(se, off, 64);
      cnt += __shfl_down(cnt, off, 64);
    }
    int lane = tid & 63, wv = tid >> 6;
    if (lane == 0) { red[0][wv] = num; red[1][wv] = den; red[2][wv] = se; red[3][wv] = cnt; }
    __syncthreads();
    if (tid == 0) {
      ws[lb * 2 + 0] = red[0][0] + red[0][1] + red[0][2] + red[0][3];
      ws[lb * 2 + 1] = red[1][0] + red[1][1] + red[1][2] + red[1][3];
      if (tile == 0) {
        float se_t = red[2][0] + red[2][1] + red[2][2] + red[2][3];
        float cnt_t = red[3][0] + red[3][1] + red[3][2] + red[3][3];
        ws[2048 + b] = se_t / (3.f * fmaxf(cnt_t, 1.f));
      }
    }
  }
}

__global__ __launch_bounds__(256) void finalize_kernel(const float* __restrict__ ws,
                                                       float* __restrict__ out) {
  const int tid = threadIdx.x;
  __shared__ float sred[4][4];

  // sidechain partial sums
  const float* sc = ws + 2112;
  float s0 = 0.f, s1 = 0.f, s2 = 0.f, s3 = 0.f;
  for (int i = tid; i < 512; i += 256) {
    s0 += sc[4 * i + 0]; s1 += sc[4 * i + 1]; s2 += sc[4 * i + 2]; s3 += sc[4 * i + 3];
  }
  for (int off = 32; off > 0; off >>= 1) {
    s0 += __shfl_down(s0, off, 64);
    s1 += __shfl_down(s1, off, 64);
    s2 += __shfl_down(s2, off, 64);
    s3 += __shfl_down(s3, off, 64);
  }
  int lane = tid & 63, wv = tid >> 6;
  if (lane == 0) { sred[0][wv] = s0; sred[1][wv] = s1; sred[2][wv] = s2; sred[3][wv] = s3; }
  __syncthreads();

  // ligand: wave 0, one batch per lane
  float lval = 0.f, lhas = 0.f, lcoord = 0.f;
  if (tid < 64) {
    float n = 0.f, d = 0.f;
    for (int t = 0; t < 16; t++) {
      n += ws[(tid * 16 + t) * 2 + 0];
      d += ws[(tid * 16 + t) * 2 + 1];
    }
    lval = (d > 0.f) ? n / fmaxf(d, 1.f) : 0.f;
    lhas = (d > 0.f) ? 1.f : 0.f;
    lcoord = ws[2048 + tid];
    for (int off = 32; off > 0; off >>= 1) {
      lval += __shfl_down(lval, off, 64);
      lhas += __shfl_down(lhas, off, 64);
      lcoord += __shfl_down(lcoord, off, 64);
    }
  }
  if (tid == 0) {
    float sc_mse = sred[0][0] + sred[0][1] + sred[0][2] + sred[0][3];
    float sc_am = sred[1][0] + sred[1][1] + sred[1][2] + sred[1][3];
    float sc_val = sred[2][0] + sred[2][1] + sred[2][2] + sred[2][3];
    float sc_has = sred[3][0] + sred[3][1] + sred[3][2] + sred[3][3];
    float ligand_loss = lcoord * (1.f / 64.f);
    float ligand_dist_loss = lval / fmaxf(lhas, 1.f);
    float sidechain_loss = sc_mse / fmaxf(sc_am, 1.f);
    float sidechain_dist_loss = sc_val / fmaxf(sc_has, 1.f);
    out[0] = ligand_loss + 0.2f * ligand_dist_loss + 0.5f * sidechain_loss +
             0.1f * sidechain_dist_loss;
  }
}

extern "C" void kernel_launch(void* const* d_in, const int* in_sizes, int n_in,
                              void* d_out, int out_size, void* d_ws, size_t ws_size,
                              hipStream_t stream) {
  const float* ligand_pred = (const float*)d_in[0];
  const float* ligand_tgt = (const float*)d_in[1];
  const float* sidechain_pred = (const float*)d_in[2];
  const float* sidechain_tgt = (const float*)d_in[3];
  const int* ligand_mask = (const int*)d_in[4];
  const int* atom_mask = (const int*)d_in[5];
  float* out = (float*)d_out;
  float* ws = (float*)d_ws;

  fused_kernel<<<GRID, 256, 0, stream>>>(ligand_pred, ligand_tgt, ligand_mask,
                                         sidechain_pred, sidechain_tgt, atom_mask, ws);
  finalize_kernel<<<1, 256, 0, stream>>>(ws, out);
}

// Round 5
// 106.730 us; speedup vs baseline: 1.6493x; 1.0098x over previous
//
#include <hip/hip_runtime.h>

#define CUTOFF 5.0f
#define DEPS 1e-12f
#define FSQRT(x) __builtin_amdgcn_sqrtf(x)

// ws float layout (every slot written unconditionally every launch):
//  [0, 1024)     lig_part[512][2]  (num, den) per ligand block
//  [1024, 1088)  lig_coord[64]     per-batch coord ratio (tile-0 blocks)
//  [1088, 3136)  sc_part[512][4]   (mse, am, val, has) per sidechain block

#define NSC_BLK 512   // 512 blocks * 128 groups (2 lanes/group, 256 thr)
#define NLIG_BLK 512  // 64 batches * 8 i-tiles (64-wide)
#define GRID (NSC_BLK + NLIG_BLK)

__global__ __launch_bounds__(256) void fused_kernel(
    const float* __restrict__ lig_pred, const float* __restrict__ lig_tgt,
    const int* __restrict__ lig_mask,
    const float* __restrict__ sc_pred, const float* __restrict__ sc_tgt,
    const int* __restrict__ sc_mask,
    float* __restrict__ ws) {
  const int tid = threadIdx.x;
  __shared__ float4 stage4[1344];  // 21.5 KB; sc staging / ligand i-tiles (aliased)
  __shared__ float red[4][4];

  if (blockIdx.x < NSC_BLK) {
    // ================= sidechain: 2 lanes per group =================
    // lane = 2*gl + p; lane owns atoms [p*7, p*7+7) of group gl.
    float ax[7], ay[7], az[7];  // pred, own atoms
    float bx[7], by[7], bz[7];  // tgt, own atoms
    float m[7];

    // stage pred chunk (128 groups * 42 floats = 5376 floats) coalesced
    const float4* srcp = (const float4*)(sc_pred + (size_t)blockIdx.x * 5376);
    for (int k = tid; k < 1344; k += 256) stage4[k] = srcp[k];
    __syncthreads();
    {
      const float* s = ((const float*)stage4) + tid * 21;  // gcd(21,32)=1: no conflicts
#pragma unroll
      for (int a = 0; a < 7; a++) { ax[a] = s[3 * a]; ay[a] = s[3 * a + 1]; az[a] = s[3 * a + 2]; }
    }
    __syncthreads();
    const float4* srct = (const float4*)(sc_tgt + (size_t)blockIdx.x * 5376);
    for (int k = tid; k < 1344; k += 256) stage4[k] = srct[k];
    __syncthreads();
    {
      const float* s = ((const float*)stage4) + tid * 21;
#pragma unroll
      for (int a = 0; a < 7; a++) { bx[a] = s[3 * a]; by[a] = s[3 * a + 1]; bz[a] = s[3 * a + 2]; }
    }
    // masks: 7 ints/lane, contiguous per lane
    const int* mp = sc_mask + (size_t)blockIdx.x * 1792 + tid * 7;
#pragma unroll
    for (int a = 0; a < 7; a++) m[a] = (mp[a] != 0) ? 1.f : 0.f;

    // per-atom coord mse over own half
    float mse = 0.f, am = 0.f;
#pragma unroll
    for (int a = 0; a < 7; a++) {
      float dx = ax[a] - bx[a], dy = ay[a] - by[a], dz = az[a] - bz[a];
      mse += m[a] * ((dx * dx + dy * dy + dz * dz) * (1.f / 3.f));
      am += m[a];
    }

    // pair loop: i over own 7, j over all 14 (own + partner via shfl_xor).
    // Full ordered matrix across the lane pair == reference's dmask sum;
    // diagonal i==j gives tsq==0 exactly -> excluded.
    float num = 0.f, den = 0.f;
#pragma unroll
    for (int js = 0; js < 7; js++) {
#pragma unroll
      for (int side = 0; side < 2; side++) {
        float jx, jy, jz, kx, ky, kz, mj;
        if (side == 0) {
          jx = ax[js]; jy = ay[js]; jz = az[js];
          kx = bx[js]; ky = by[js]; kz = bz[js];
          mj = m[js];
        } else {
          jx = __shfl_xor(ax[js], 1, 64); jy = __shfl_xor(ay[js], 1, 64);
          jz = __shfl_xor(az[js], 1, 64);
          kx = __shfl_xor(bx[js], 1, 64); ky = __shfl_xor(by[js], 1, 64);
          kz = __shfl_xor(bz[js], 1, 64);
          mj = __shfl_xor(m[js], 1, 64);
        }
#pragma unroll
        for (int i = 0; i < 7; i++) {
          float dx = bx[i] - kx, dy = by[i] - ky, dz = bz[i] - kz;
          float tsq = dx * dx + dy * dy + dz * dz;
          float td = FSQRT(fmaxf(tsq, DEPS));
          float w = m[i] * mj;
          w = (tsq > 0.f) ? w : 0.f;
          w = (td <= CUTOFF) ? w : 0.f;
          float qx = ax[i] - jx, qy = ay[i] - jy, qz = az[i] - jz;
          float pd = FSQRT(fmaxf(qx * qx + qy * qy + qz * qz, DEPS));
          float d = pd - td;
          num += w * d * d;
          den += w;
        }
      }
    }
    // combine lane pair -> per-group val/has; each lane contributes half
    float num_g = num + __shfl_xor(num, 1, 64);
    float den_g = den + __shfl_xor(den, 1, 64);
    float val = (den_g > 0.f) ? 0.5f * (num_g / fmaxf(den_g, 1.f)) : 0.f;
    float has = (den_g > 0.f) ? 0.5f : 0.f;

    for (int off = 32; off > 0; off >>= 1) {
      mse += __shfl_down(mse, off, 64);
      am += __shfl_down(am, off, 64);
      val += __shfl_down(val, off, 64);
      has += __shfl_down(has, off, 64);
    }
    int lane = tid & 63, wv = tid >> 6;
    if (lane == 0) { red[0][wv] = mse; red[1][wv] = am; red[2][wv] = val; red[3][wv] = has; }
    __syncthreads();
    if (tid == 0) {
      float* p = ws + 1088 + (size_t)blockIdx.x * 4;
      p[0] = red[0][0] + red[0][1] + red[0][2] + red[0][3];
      p[1] = red[1][0] + red[1][1] + red[1][2] + red[1][3];
      p[2] = red[2][0] + red[2][1] + red[2][2] + red[2][3];
      p[3] = red[3][0] + red[3][1] + red[3][2] + red[3][3];
    }
  } else {
    // ============ ligand: block = (batch, 64-wide i-tile), 8 tiles ============
    const int L = 512;
    const int lb = blockIdx.x - NSC_BLK;
    const int b = lb >> 3;
    const int tile = lb & 7;
    const int i0 = tile * 64;
    const float* pb = lig_pred + (size_t)b * L * 3;
    const float* tb = lig_tgt + (size_t)b * L * 3;
    const int* mb = lig_mask + (size_t)b * L;

    float4* st4 = stage4;       // i-tile tgt xyz + mask [64]
    float4* sp4 = stage4 + 64;  // i-tile pred xyz [64]

    // 2 j-atoms per thread in registers
    float pjx[2], pjy[2], pjz[2], tjx[2], tjy[2], tjz[2], mj[2];
#pragma unroll
    for (int k = 0; k < 2; k++) {
      int j = k * 256 + tid;
      pjx[k] = pb[3 * j]; pjy[k] = pb[3 * j + 1]; pjz[k] = pb[3 * j + 2];
      tjx[k] = tb[3 * j]; tjy[k] = tb[3 * j + 1]; tjz[k] = tb[3 * j + 2];
      mj[k] = (mb[j] != 0) ? 1.f : 0.f;
    }
    if (tid < 64) {
      int i = i0 + tid;
      st4[tid] = make_float4(tb[3 * i], tb[3 * i + 1], tb[3 * i + 2], (mb[i] != 0) ? 1.f : 0.f);
    } else if (tid < 128) {
      int i = i0 + tid - 64;
      sp4[tid - 64] = make_float4(pb[3 * i], pb[3 * i + 1], pb[3 * i + 2], 0.f);
    }
    __syncthreads();

    float se = 0.f, cnt = 0.f;
    if (tile == 0) {
#pragma unroll
      for (int k = 0; k < 2; k++) {
        float dx = pjx[k] - tjx[k], dy = pjy[k] - tjy[k], dz = pjz[k] - tjz[k];
        se += mj[k] * (dx * dx + dy * dy + dz * dz);
        cnt += mj[k];
      }
    }

    float num = 0.f, den = 0.f;
#pragma unroll 4
    for (int ii = 0; ii < 64; ii++) {
      float4 ti = st4[ii];  // wave-uniform address -> broadcast ds_read_b128
      float4 pi = sp4[ii];
#pragma unroll
      for (int k = 0; k < 2; k++) {
        float w = ti.w * mj[k];
        float dx = ti.x - tjx[k], dy = ti.y - tjy[k], dz = ti.z - tjz[k];
        float tsq = dx * dx + dy * dy + dz * dz;
        float td = FSQRT(fmaxf(tsq, DEPS));
        w = (tsq > 0.f) ? w : 0.f;
        w = (td <= CUTOFF) ? w : 0.f;
        float qx = pi.x - pjx[k], qy = pi.y - pjy[k], qz = pi.z - pjz[k];
        float pd = FSQRT(fmaxf(qx * qx + qy * qy + qz * qz, DEPS));
        float d = pd - td;
        num += w * d * d;
        den += w;
      }
    }

    for (int off = 32; off > 0; off >>= 1) {
      num += __shfl_down(num, off, 64);
      den += __shfl_down(den, off, 64);
      se += __shfl_down(se, off, 64);
      cnt += __shfl_down(cnt, off, 64);
    }
    int lane = tid & 63, wv = tid >> 6;
    if (lane == 0) { red[0][wv] = num; red[1][wv] = den; red[2][wv] = se; red[3][wv] = cnt; }
    __syncthreads();
    if (tid == 0) {
      ws[lb * 2 + 0] = red[0][0] + red[0][1] + red[0][2] + red[0][3];
      ws[lb * 2 + 1] = red[1][0] + red[1][1] + red[1][2] + red[1][3];
      if (tile == 0) {
        float se_t = red[2][0] + red[2][1] + red[2][2] + red[2][3];
        float cnt_t = red[3][0] + red[3][1] + red[3][2] + red[3][3];
        ws[1024 + b] = se_t / (3.f * fmaxf(cnt_t, 1.f));
      }
    }
  }
}

__global__ __launch_bounds__(256) void finalize_kernel(const float* __restrict__ ws,
                                                       float* __restrict__ out) {
  const int tid = threadIdx.x;
  __shared__ float sred[4][4];

  // sidechain partial sums
  const float* sc = ws + 1088;
  float s0 = 0.f, s1 = 0.f, s2 = 0.f, s3 = 0.f;
  for (int i = tid; i < 512; i += 256) {
    s0 += sc[4 * i + 0]; s1 += sc[4 * i + 1]; s2 += sc[4 * i + 2]; s3 += sc[4 * i + 3];
  }
  for (int off = 32; off > 0; off >>= 1) {
    s0 += __shfl_down(s0, off, 64);
    s1 += __shfl_down(s1, off, 64);
    s2 += __shfl_down(s2, off, 64);
    s3 += __shfl_down(s3, off, 64);
  }
  int lane = tid & 63, wv = tid >> 6;
  if (lane == 0) { sred[0][wv] = s0; sred[1][wv] = s1; sred[2][wv] = s2; sred[3][wv] = s3; }
  __syncthreads();

  // ligand: wave 0, one batch per lane
  float lval = 0.f, lhas = 0.f, lcoord = 0.f;
  if (tid < 64) {
    float n = 0.f, d = 0.f;
    for (int t = 0; t < 8; t++) {
      n += ws[(tid * 8 + t) * 2 + 0];
      d += ws[(tid * 8 + t) * 2 + 1];
    }
    lval = (d > 0.f) ? n / fmaxf(d, 1.f) : 0.f;
    lhas = (d > 0.f) ? 1.f : 0.f;
    lcoord = ws[1024 + tid];
    for (int off = 32; off > 0; off >>= 1) {
      lval += __shfl_down(lval, off, 64);
      lhas += __shfl_down(lhas, off, 64);
      lcoord += __shfl_down(lcoord, off, 64);
    }
  }
  if (tid == 0) {
    float sc_mse = sred[0][0] + sred[0][1] + sred[0][2] + sred[0][3];
    float sc_am = sred[1][0] + sred[1][1] + sred[1][2] + sred[1][3];
    float sc_val = sred[2][0] + sred[2][1] + sred[2][2] + sred[2][3];
    float sc_has = sred[3][0] + sred[3][1] + sred[3][2] + sred[3][3];
    float ligand_loss = lcoord * (1.f / 64.f);
    float ligand_dist_loss = lval / fmaxf(lhas, 1.f);
    float sidechain_loss = sc_mse / fmaxf(sc_am, 1.f);
    float sidechain_dist_loss = sc_val / fmaxf(sc_has, 1.f);
    out[0] = ligand_loss + 0.2f * ligand_dist_loss + 0.5f * sidechain_loss +
             0.1f * sidechain_dist_loss;
  }
}

extern "C" void kernel_launch(void* const* d_in, const int* in_sizes, int n_in,
                              void* d_out, int out_size, void* d_ws, size_t ws_size,
                              hipStream_t stream) {
  const float* ligand_pred = (const float*)d_in[0];
  const float* ligand_tgt = (const float*)d_in[1];
  const float* sidechain_pred = (const float*)d_in[2];
  const float* sidechain_tgt = (const float*)d_in[3];
  const int* ligand_mask = (const int*)d_in[4];
  const int* atom_mask = (const int*)d_in[5];
  float* out = (float*)d_out;
  float* ws = (float*)d_ws;

  fused_kernel<<<GRID, 256, 0, stream>>>(ligand_pred, ligand_tgt, ligand_mask,
                                         sidechain_pred, sidechain_tgt, atom_mask, ws);
  finalize_kernel<<<1, 256, 0, stream>>>(ws, out);
}